// Round 4
// baseline (1019.786 us; speedup 1.0000x reference)
//
#include <hip/hip_runtime.h>

#define BB  512
#define SS  100
#define DD  512
#define DFF 256
#define HIDN 230
#define LDA 520   // padded LDS row stride (bf16 elems)

typedef unsigned short u16;
typedef unsigned int   u32;
typedef __attribute__((ext_vector_type(8))) short v8s;  // 8 bf16 (4 VGPRs) MFMA frag
typedef __attribute__((ext_vector_type(4))) float v4f;  // 4 f32 accum

__device__ __forceinline__ float b2f(u16 u){
  union { u32 i; float f; } v; v.i = ((u32)u) << 16; return v.f;
}
__device__ __forceinline__ u16 f2b(float f){
  union { float f; u32 i; } v; v.f = f;
  u32 r = (v.i + 0x7fffu + ((v.i >> 16) & 1u)) >> 16;  // RNE
  return (u16)r;
}
__device__ __forceinline__ float rsum16(float s){
  #pragma unroll
  for (int o = 1; o < 16; o <<= 1) s += __shfl_xor(s, o, 64);
  return s;
}

// one 16x16 output tile, K-dot via mfma_f32_16x16x32_bf16
// arow = &Abuf[lane&15][(lane>>4)*8], wrow = W + n_row*K + (lane>>4)*8  (W row-major [N][K], bf16)
template<int K>
__device__ __forceinline__ v4f tile_mm(const u16* arow, const u16* wrow){
  v4f acc = {0.f, 0.f, 0.f, 0.f};
  #pragma unroll
  for (int k0 = 0; k0 < K; k0 += 32){
    v8s af = *(const v8s*)(arow + k0);
    v8s bf = *(const v8s*)(wrow + k0);
    acc = __builtin_amdgcn_mfma_f32_16x16x32_bf16(af, bf, acc, 0, 0, 0);
  }
  return acc;
}

// custom LN (unbiased std, eps added to std) over 512 cols; 16 threads per row.
__device__ __forceinline__ void ln_custom_pass(int lrow, int lc,
    const u16 (*src)[LDA], u16 (*dst)[LDA], const u16 (*addb)[LDA],
    const u16* __restrict__ g, const u16* __restrict__ bb)
{
  float v[32]; float s = 0.f;
  #pragma unroll
  for (int j = 0; j < 32; j++){ int col = lc + j*16; float x = b2f(src[lrow][col]); v[j] = x; s += x; }
  s = rsum16(s);
  float mean = s * (1.0f/512.0f);
  float vs = 0.f;
  #pragma unroll
  for (int j = 0; j < 32; j++){ float d = v[j] - mean; vs += d*d; }
  vs = rsum16(vs);
  float inv = 1.0f / (sqrtf(vs * (1.0f/511.0f)) + 1e-6f);
  #pragma unroll
  for (int j = 0; j < 32; j++){
    int col = lc + j*16;
    float r = b2f(g[col]) * (v[j] - mean) * inv + b2f(bb[col]);
    if (addb) r += b2f(addb[lrow][col]);
    dst[lrow][col] = f2b(r);
  }
}

// ---------------- k_cvt: convert f32 weight/vector tensors -> bf16 in ws ----------------
#define NSEG 20
struct CvtArgs {
  const float* src[NSEG];
  u16* dst;
  int off[NSEG];
  int n[NSEG];
};
__global__ __launch_bounds__(256) void k_cvt(CvtArgs a){
  int total = a.off[NSEG-1] + a.n[NSEG-1];
  for (int i = blockIdx.x*blockDim.x + threadIdx.x; i < total; i += gridDim.x*blockDim.x){
    int s = 0;
    #pragma unroll
    for (int j = 1; j < NSEG; j++) if (i >= a.off[j]) s = j;
    a.dst[i] = f2b(a.src[s][i - a.off[s]]);
  }
}

// ---------------- K1: per-batch attention collapse (all f32) ----------------
// a_m[b,:] = fc(ctx_masked-row), a_u[b,:] = fc(ctx_unmasked-row)  (both include fc_b)
__global__ __launch_bounds__(256) void k_batch(
    const float* __restrict__ inp, const int* __restrict__ mask,
    const float* __restrict__ wv, const float* __restrict__ bv,
    const float* __restrict__ fcw, const float* __restrict__ fcb,
    float* __restrict__ a_m, float* __restrict__ a_u)
{
  __shared__ float sia[DD], sim[DD], cm[DD], cu[DD];
  __shared__ int ncnt;
  const int b = blockIdx.x, t = threadIdx.x;
  if (t == 0){
    int c = 0;
    for (int s = 0; s < SS; s++) c += (mask[b*SS + s] != 0);
    ncnt = c;
  }
  const float* base = inp + (size_t)b * SS * DD;
  float aa0 = 0, aa1 = 0, am0 = 0, am1 = 0;
  for (int s = 0; s < SS; s++){
    float x0 = base[s*DD + t];
    float x1 = base[s*DD + t + 256];
    aa0 += x0; aa1 += x1;
    if (mask[b*SS + s]){ am0 += x0; am1 += x1; }
  }
  sia[t] = aa0; sia[t+256] = aa1; sim[t] = am0; sim[t+256] = am1;
  __syncthreads();
  const int n = ncnt;
  // softmax over {1 (x n), 1e-8 (x S-n)}: stable-softmax -> exp(0)=1, exp(1e-8-1)=expf(-1.0f)
  const float e0 = expf(1e-8f - 1.0f);
  const float denom = (float)n + (float)(SS - n) * e0;
  const float p1 = 1.0f / denom, p0 = e0 / denom;
  #pragma unroll
  for (int dd = 0; dd < 2; dd++){
    int d = t + dd*256;
    const float4* wr = (const float4*)(wv + (size_t)d * DD);
    float sva = 0.f, svm = 0.f;
    for (int k4 = 0; k4 < DD/4; k4++){
      float4 w = wr[k4];
      int kb = k4*4;
      sva += w.x*sia[kb] + w.y*sia[kb+1] + w.z*sia[kb+2] + w.w*sia[kb+3];
      svm += w.x*sim[kb] + w.y*sim[kb+1] + w.z*sim[kb+2] + w.w*sim[kb+3];
    }
    float bvd = bv[d];
    sva += (float)SS * bvd;     // sum_t v[t][d] over all rows
    svm += (float)n  * bvd;     // sum over masked rows
    cm[d] = p1*svm + p0*(sva - svm);
    cu[d] = sva * (1.0f/(float)SS);
  }
  __syncthreads();
  #pragma unroll
  for (int dd = 0; dd < 2; dd++){
    int d = t + dd*256;
    const float4* fr = (const float4*)(fcw + (size_t)d * DD);
    float xm = 0.f, xu = 0.f;
    for (int k4 = 0; k4 < DD/4; k4++){
      float4 w = fr[k4];
      int kb = k4*4;
      xm += w.x*cm[kb] + w.y*cm[kb+1] + w.z*cm[kb+2] + w.w*cm[kb+3];
      xu += w.x*cu[kb] + w.y*cu[kb+1] + w.z*cu[kb+2] + w.w*cu[kb+3];
    }
    float fb = fcb[d];
    a_m[(size_t)b*DD + d] = xm + fb;
    a_u[(size_t)b*DD + d] = xu + fb;
  }
}

// ---------------- K2: fused per-row chain, 16 rows/block ----------------
__global__ __launch_bounds__(256) void k_main(
    const float* __restrict__ inp, const int* __restrict__ mask,
    const u16* __restrict__ lnm_g, const u16* __restrict__ lnm_b,
    const u16* __restrict__ w1,   const u16* __restrict__ b1,
    const u16* __restrict__ w2,   const u16* __restrict__ b2,
    const u16* __restrict__ lpc_w, const u16* __restrict__ lpc_b,
    const u16* __restrict__ lnc_g, const u16* __restrict__ lnc_b,
    const u16* __restrict__ pwf_w, const u16* __restrict__ pwf_b,
    const u16* __restrict__ lpi_w, const u16* __restrict__ lpi_b,
    const u16* __restrict__ lni_g, const u16* __restrict__ lni_b,
    const u16* __restrict__ lnf_g, const u16* __restrict__ lnf_b,
    const u16* __restrict__ mlpf_w, const u16* __restrict__ mlpf_b,
    const float* __restrict__ a_m, const float* __restrict__ a_u,
    float* __restrict__ out)
{
  __shared__ __align__(16) u16 XIN[16][LDA];  // x (inp rows bf16), later (rv+res_inp) staging
  __shared__ __align__(16) u16 Ab[16][LDA];   // current GEMM A operand
  __shared__ __align__(16) u16 Ob[16][LDA];   // GEMM outputs / pre-LN staging

  const int tid  = threadIdx.x;
  const int lane = tid & 63, wid = tid >> 6;
  const int m = lane & 15, q = lane >> 4;
  const int r0 = blockIdx.x * 16;
  const int lrow = tid >> 4, lc = tid & 15;   // LN pass: 16 threads per row

  // ---- load 16 inp rows (f32 -> bf16): 4 iters x 256 thr x 8 floats = 8192 = 16*512 ----
  #pragma unroll
  for (int c = 0; c < 4; c++){
    int e = c*2048 + tid*8;                   // element index in [0, 8192)
    int row = e >> 9, col = e & 511;
    const float4* p = (const float4*)(inp + (size_t)(r0 + row) * DD + col);
    float4 v0 = p[0], v1 = p[1];
    uint4 o;
    o.x = (u32)f2b(v0.x) | ((u32)f2b(v0.y) << 16);
    o.y = (u32)f2b(v0.z) | ((u32)f2b(v0.w) << 16);
    o.z = (u32)f2b(v1.x) | ((u32)f2b(v1.y) << 16);
    o.w = (u32)f2b(v1.z) | ((u32)f2b(v1.w) << 16);
    *(uint4*)&XIN[row][col] = o;
  }
  __syncthreads();

  // ---- LN1 (torch LN): mha = LN(a_sel + x) -> Ab ----
  {
    int Rg = r0 + lrow;
    int bi = Rg / SS;
    const float* asel = (mask[Rg] ? a_m : a_u) + (size_t)bi * DD;
    float v[32]; float s = 0.f;
    #pragma unroll
    for (int j = 0; j < 32; j++){
      int col = lc + j*16;
      float x = asel[col] + b2f(XIN[lrow][col]);
      v[j] = x; s += x;
    }
    s = rsum16(s);
    float mean = s * (1.0f/512.0f);
    float vs = 0.f;
    #pragma unroll
    for (int j = 0; j < 32; j++){ float d = v[j] - mean; vs += d*d; }
    vs = rsum16(vs);
    float inv = 1.0f / sqrtf(vs * (1.0f/512.0f) + 1e-5f);
    #pragma unroll
    for (int j = 0; j < 32; j++){
      int col = lc + j*16;
      float r = b2f(lnm_g[col]) * (v[j] - mean) * inv + b2f(lnm_b[col]);
      Ab[lrow][col] = f2b(r);
    }
  }
  __syncthreads();

  // ---- GEMM1: h1 = relu(mha @ w1^T + b1) -> Ob[:,0:256] ----
  for (int t = wid; t < 16; t += 4){
    int col = t*16 + m;
    v4f acc = tile_mm<512>(&Ab[m][q*8], w1 + (size_t)col*512 + q*8);
    float bias = b2f(b1[col]);
    #pragma unroll
    for (int i = 0; i < 4; i++){
      float val = acc[i] + bias;
      Ob[q*4+i][col] = f2b(val > 0.f ? val : 0.f);
    }
  }
  __syncthreads();

  // ---- GEMM2: ffn = h1 @ w2^T + b2 ; stage (ffn + mha) -> Ob (after sync) ----
  {
    v4f accs[8];
    #pragma unroll
    for (int ti = 0; ti < 8; ti++){
      int col = (wid + ti*4)*16 + m;
      accs[ti] = tile_mm<256>(&Ob[m][q*8], w2 + (size_t)col*256 + q*8);
    }
    __syncthreads();   // everyone done reading h1 from Ob
    #pragma unroll
    for (int ti = 0; ti < 8; ti++){
      int col = (wid + ti*4)*16 + m;
      float bias = b2f(b2[col]);
      #pragma unroll
      for (int i = 0; i < 4; i++){
        int row = q*4 + i;
        Ob[row][col] = f2b(accs[ti][i] + bias + b2f(Ab[row][col]));  // + mha residual
      }
    }
  }
  __syncthreads();

  // ---- LN2 (custom, lni): ctx2 = LNc(ffn+mha); y = ctx2 + x -> Ab ----
  ln_custom_pass(lrow, lc, Ob, Ab, XIN, lni_g, lni_b);
  __syncthreads();

  // ---- GEMM3: z = y @ lpc_w^T + 2*lpc_b -> Ob ----
  for (int t = wid; t < 32; t += 4){
    int col = t*16 + m;
    v4f acc = tile_mm<512>(&Ab[m][q*8], lpc_w + (size_t)col*512 + q*8);
    float bias = 2.0f * b2f(lpc_b[col]);
    #pragma unroll
    for (int i = 0; i < 4; i++) Ob[q*4+i][col] = f2b(acc[i] + bias);
  }
  __syncthreads();

  // ---- LN3 (custom, lnc): res_inp = LNc(z) -> Ab ----
  ln_custom_pass(lrow, lc, Ob, Ab, (const u16 (*)[LDA])nullptr, lnc_g, lnc_b);
  __syncthreads();

  // ---- GEMM4: h2 = relu(res_inp @ pwf^T + pwf_b) -> Ob[:,0:256] ----
  for (int t = wid; t < 16; t += 4){
    int col = t*16 + m;
    v4f acc = tile_mm<512>(&Ab[m][q*8], pwf_w + (size_t)col*512 + q*8);
    float bias = b2f(pwf_b[col]);
    #pragma unroll
    for (int i = 0; i < 4; i++){
      float val = acc[i] + bias;
      Ob[q*4+i][col] = f2b(val > 0.f ? val : 0.f);
    }
  }
  __syncthreads();

  // ---- GEMM5: rv = h2 @ lpi^T + lpi_b ; stage (rv + res_inp) -> XIN (x is dead) ----
  for (int t = wid; t < 32; t += 4){
    int col = t*16 + m;
    v4f acc = tile_mm<256>(&Ob[m][q*8], lpi_w + (size_t)col*256 + q*8);
    float bias = b2f(lpi_b[col]);
    #pragma unroll
    for (int i = 0; i < 4; i++){
      int row = q*4 + i;
      XIN[row][col] = f2b(acc[i] + bias + b2f(Ab[row][col]));  // + res_inp residual
    }
  }
  __syncthreads();

  // ---- LN4 (custom, lnf): res = LNc(rv+res_inp) -> Ab ----
  ln_custom_pass(lrow, lc, XIN, Ab, (const u16 (*)[LDA])nullptr, lnf_g, lnf_b);
  __syncthreads();

  // ---- GEMM6: out = res @ mlpf^T + mlpf_b  (N=230, guarded) -- f32 STORES ----
  for (int t = wid; t < 15; t += 4){
    int col = t*16 + m;
    int wr = col < HIDN ? col : (HIDN - 1);   // stay in-bounds; garbage cols never stored
    v4f acc = tile_mm<512>(&Ab[m][q*8], mlpf_w + (size_t)wr*512 + q*8);
    if (col < HIDN){
      float bias = b2f(mlpf_b[col]);
      #pragma unroll
      for (int i = 0; i < 4; i++){
        int row = q*4 + i;
        out[(size_t)(r0 + row)*HIDN + col] = acc[i] + bias;   // float32 output
      }
    }
  }
}

extern "C" void kernel_launch(void* const* d_in, const int* in_sizes, int n_in,
                              void* d_out, int out_size, void* d_ws, size_t ws_size,
                              hipStream_t stream)
{
  const float* inp    = (const float*)d_in[0];
  const int*   mask   = (const int*)d_in[1];
  // d_in[2] = gate: dead computation in the reference
  const float* wv     = (const float*)d_in[3];
  const float* bv     = (const float*)d_in[4];
  const float* fc_w   = (const float*)d_in[5];
  const float* fc_b   = (const float*)d_in[6];

  // ws layout: a_m f32[512*512] | a_u f32[512*512] | bf16 weights/vectors (~1.81 MB)
  float* a_m = (float*)d_ws;
  float* a_u = a_m + (size_t)BB * DD;
  u16* bfb = (u16*)((char*)d_ws + 2u * BB * DD * sizeof(float));

  // bf16 region offsets (elements)
  const int OW1 = 0;                       // 256x512
  const int OW2 = OW1 + DFF*DD;            // 512x256
  const int OLPC = OW2 + DD*DFF;           // 512x512
  const int OPWF = OLPC + DD*DD;           // 256x512
  const int OLPI = OPWF + DFF*DD;          // 512x256
  const int OMLPF = OLPI + DD*DFF;         // 230x512
  int voff = OMLPF + HIDN*DD;
  const int OLNMG = voff; voff += DD;
  const int OLNMB = voff; voff += DD;
  const int OB1   = voff; voff += DFF;
  const int OB2   = voff; voff += DD;
  const int OLPCB = voff; voff += DD;
  const int OLNCG = voff; voff += DD;
  const int OLNCB = voff; voff += DD;
  const int OPWFB = voff; voff += DFF;
  const int OLPIB = voff; voff += DD;
  const int OLNIG = voff; voff += DD;
  const int OLNIB = voff; voff += DD;
  const int OLNFG = voff; voff += DD;
  const int OLNFB = voff; voff += DD;
  const int OMLPFB = voff; voff += HIDN;

  CvtArgs ca;
  const int srcidx[NSEG] = {9, 11, 13, 17, 19, 25,      // w1,w2,lpc_w,pwf_w,lpi_w,mlpf_w
                            7, 8, 10, 12, 14, 15, 16, 18, 20, 21, 22, 23, 24, 26};
  const int offs[NSEG]   = {OW1, OW2, OLPC, OPWF, OLPI, OMLPF,
                            OLNMG, OLNMB, OB1, OB2, OLPCB, OLNCG, OLNCB, OPWFB,
                            OLPIB, OLNIG, OLNIB, OLNFG, OLNFB, OMLPFB};
  const int lens[NSEG]   = {DFF*DD, DD*DFF, DD*DD, DFF*DD, DD*DFF, HIDN*DD,
                            DD, DD, DFF, DD, DD, DD, DD, DFF, DD, DD, DD, DD, DD, HIDN};
  for (int i = 0; i < NSEG; i++){
    ca.src[i] = (const float*)d_in[srcidx[i]];
    ca.off[i] = offs[i];
    ca.n[i]   = lens[i];
  }
  ca.dst = bfb;

  k_cvt<<<512, 256, 0, stream>>>(ca);
  k_batch<<<BB, 256, 0, stream>>>(inp, mask, wv, bv, fc_w, fc_b, a_m, a_u);
  k_main<<<(BB*SS)/16, 256, 0, stream>>>(inp, mask,
      bfb + OLNMG, bfb + OLNMB,
      bfb + OW1,   bfb + OB1,
      bfb + OW2,   bfb + OB2,
      bfb + OLPC,  bfb + OLPCB,
      bfb + OLNCG, bfb + OLNCB,
      bfb + OPWF,  bfb + OPWFB,
      bfb + OLPI,  bfb + OLPIB,
      bfb + OLNIG, bfb + OLNIB,
      bfb + OLNFG, bfb + OLNFB,
      bfb + OMLPF, bfb + OMLPFB,
      a_m, a_u, (float*)d_out);
}